// Round 15
// baseline (629.477 us; speedup 1.0000x reference)
//
#include <hip/hip_runtime.h>
#include <hip/hip_bf16.h>

using bf16x8 = __attribute__((ext_vector_type(8))) short;
using f32x4  = __attribute__((ext_vector_type(4))) float;
using u16x4  = __attribute__((ext_vector_type(4))) unsigned short;

constexpr int Ht = 60, Wt = 108, C = 512;
constexpr int GWt = 14, NWIN = 112, NTOK = Ht * Wt, BT = 16;
constexpr int NBLK = BT * NWIN;                    // 1792 windows
constexpr int MROWS = BT * NTOK;                   // 103680 = 810*128
constexpr float SCALE = 0.08838834764831845f;      // 1/sqrt(128)
constexpr size_t WOFF  = 4 * 262144;               // weights elems (bf16)
constexpr size_t QKVE  = (size_t)MROWS * 1536;     // fused slab elems
constexpr size_t SLABE = (size_t)NBLK * 64 * 512;  // tier-2 slab elems

typedef __attribute__((address_space(3))) void lds_void;
typedef const __attribute__((address_space(1))) void g_void;
__device__ __forceinline__ void g2lds16(const void* g, void* l) {
  __builtin_amdgcn_global_load_lds((g_void*)g, (lds_void*)l, 16, 0, 0);
}

__device__ __forceinline__ unsigned short f2b(float f) {   // f32 -> bf16 RNE
  union { float f; unsigned u; } v; v.f = f;
  unsigned r = v.u + 0x7fffu + ((v.u >> 16) & 1u);
  return (unsigned short)(r >> 16);
}
__device__ __forceinline__ bf16x8 cvt8(float4 a, float4 b) {
  union { bf16x8 v; __hip_bfloat162 h[4]; } u;
  u.h[0] = __float22bfloat162_rn(make_float2(a.x, a.y));
  u.h[1] = __float22bfloat162_rn(make_float2(a.z, a.w));
  u.h[2] = __float22bfloat162_rn(make_float2(b.x, b.y));
  u.h[3] = __float22bfloat162_rn(make_float2(b.z, b.w));
  return u.v;
}

__global__ void cvt_weights(const float* __restrict__ a, const float* __restrict__ b,
                            const float* __restrict__ c, const float* __restrict__ d,
                            unsigned short* __restrict__ dst) {
  int i = blockIdx.x * blockDim.x + threadIdx.x;
  int m  = i >> 16;
  int o4 = i & 65535;
  const float* src = (m == 0) ? a : (m == 1) ? b : (m == 2) ? c : d;
  float4 v = *(const float4*)(src + (size_t)o4 * 4);
  u16x4 o;
  o[0] = f2b(v.x); o[1] = f2b(v.y); o[2] = f2b(v.z); o[3] = f2b(v.w);
  *(u16x4*)(dst + (size_t)m * 262144 + (size_t)o4 * 4) = o;
}

// ===== K1: fused QKV GEMM, A from x f32 (reg-staged cvt), B via g2lds ========
// [103680x512] @ [1536x512]^T; 128x128 tile, BK=64, XCD tile-major swizzle.
extern "C" __global__ __launch_bounds__(256, 3)
void qkv_f32(const float* __restrict__ x,            // [MROWS][512] f32
             const unsigned short* __restrict__ wf,  // [1536][512] bf16 fused
             const float* __restrict__ bq, const float* __restrict__ bk,
             const float* __restrict__ bv,
             unsigned short* __restrict__ qkvs)      // [MROWS][1536] bf16
{
  __shared__ char As[16384];   // [128][64] bf16, phys chunk = logical ^ (row&7)
  __shared__ char Bs[16384];

  const int tid   = threadIdx.x;
  const int wvid  = tid >> 6;
  const int lane  = tid & 63;
  const int l15   = lane & 15;
  const int rbase = (lane >> 4) << 2;

  const int i    = blockIdx.x;
  const int work = (i & 7) * 1215 + (i >> 3);
  const int t0   = (work / 12) * 128;
  const int j0   = (work % 12) * 128;

  // A staging (f32 -> bf16, reg path): thread owns row tid>>1, half tid&1
  const int srow = tid >> 1, sh = tid & 1;
  const float* gA = x + (size_t)(t0 + srow) * 512 + sh * 32;
  char* lArow = As + srow * 128;

  // B staging (global_load_lds): 8-lane groups, pre-swizzled source chunk
  const int lr = lane >> 3;
  const int lc = (lane & 7) ^ lr;
  const unsigned short* gB = wf + (size_t)(j0 + wvid * 32 + lr) * 512 + lc * 8;
  char* lB = Bs + wvid * 4096;

  f32x4 acc[4][4];
  #pragma unroll
  for (int mt = 0; mt < 4; ++mt)
    #pragma unroll
    for (int nt = 0; nt < 4; ++nt) acc[mt][nt] = (f32x4){0.f, 0.f, 0.f, 0.f};

  const int wr = (wvid >> 1) * 64, wc = (wvid & 1) * 64;

  for (int kk = 0; kk < 512; kk += 64) {
    // A: 128B contiguous f32 -> 4 bf16x8 -> swizzled ds_write_b128
    {
      const float* s = gA + kk;
      float4 f0 = *(const float4*)(s),      f1 = *(const float4*)(s + 4);
      float4 f2 = *(const float4*)(s + 8),  f3 = *(const float4*)(s + 12);
      float4 f4 = *(const float4*)(s + 16), f5 = *(const float4*)(s + 20);
      float4 f6 = *(const float4*)(s + 24), f7 = *(const float4*)(s + 28);
      bf16x8 c0 = cvt8(f0, f1), c1 = cvt8(f2, f3);
      bf16x8 c2 = cvt8(f4, f5), c3 = cvt8(f6, f7);
      const int sx = srow & 7;
      *(bf16x8*)(lArow + (((sh * 4 + 0) ^ sx) << 4)) = c0;
      *(bf16x8*)(lArow + (((sh * 4 + 1) ^ sx) << 4)) = c1;
      *(bf16x8*)(lArow + (((sh * 4 + 2) ^ sx) << 4)) = c2;
      *(bf16x8*)(lArow + (((sh * 4 + 3) ^ sx) << 4)) = c3;
    }
    // B: async global->LDS (linear dest, source pre-swizzled)
    #pragma unroll
    for (int ii = 0; ii < 4; ++ii)
      g2lds16(gB + (size_t)ii * 8 * 512 + kk, lB + ii * 1024);
    __syncthreads();
    #pragma unroll
    for (int ks = 0; ks < 2; ++ks) {
      const int lchunk = ks * 4 + (lane >> 4);
      bf16x8 afr[4], bfr[4];
      #pragma unroll
      for (int mt = 0; mt < 4; ++mt) {
        int row = wr + mt * 16 + l15;
        afr[mt] = *(const bf16x8*)(As + row * 128 + ((lchunk ^ (row & 7)) << 4));
      }
      #pragma unroll
      for (int nt = 0; nt < 4; ++nt) {
        int col = wc + nt * 16 + l15;
        bfr[nt] = *(const bf16x8*)(Bs + col * 128 + ((lchunk ^ (col & 7)) << 4));
      }
      #pragma unroll
      for (int mt = 0; mt < 4; ++mt)
        #pragma unroll
        for (int nt = 0; nt < 4; ++nt)
          acc[mt][nt] = __builtin_amdgcn_mfma_f32_16x16x32_bf16(afr[mt], bfr[nt], acc[mt][nt], 0, 0, 0);
    }
    __syncthreads();
  }

  const int mloc = j0 >> 9;
  const float* bias = (mloc == 0) ? bq : (mloc == 1) ? bk : bv;
  const int jb = j0 & 511;
  #pragma unroll
  for (int nt = 0; nt < 4; ++nt) {
    int col = wc + nt * 16 + l15;
    float bi = bias[jb + col];
    #pragma unroll
    for (int mt = 0; mt < 4; ++mt)
      #pragma unroll
      for (int rg = 0; rg < 4; ++rg) {
        int row = t0 + wr + mt * 16 + rbase + rg;
        qkvs[(size_t)row * 1536 + j0 + col] = f2b(acc[mt][nt][rg] + bi);
      }
  }
}

// ===== K2: per-(window,head) attention. Q staged in LDS, buffer reused as P =
extern "C" __global__ __launch_bounds__(256, 3)
void attn_tok(unsigned short* __restrict__ qkvs,    // Q cols aliased as attn out
              const float* __restrict__ bk, const float* __restrict__ bv)
{
  __shared__ char kbuf[16384];
  __shared__ char vtb[16384];
  __shared__ char qpb[16384];          // Q [64][128] swz; reused as P [64][64]

  const int tid   = threadIdx.x;
  const int wvid  = tid >> 6;
  const int lane  = tid & 63;
  const int l15   = lane & 15;
  const int kl    = (lane >> 4) << 3;
  const int rbase = (lane >> 4) << 2;

  const int w   = blockIdx.x;
  const int h   = blockIdx.y;
  const int b   = w / NWIN;
  const int win = w - b * NWIN;
  const int wy  = win / GWt, wx = win - wy * GWt;
  const int bt0 = b * NTOK;

  auto rowtok = [&](int r, bool& val) {
    int gy = wy * 8 + (r >> 3), gx = wx * 8 + (r & 7);
    val = (gy < Ht) && (gx < Wt);
    return bt0 + gy * Wt + gx;
  };

  // stage Q (comp 0, pad rows = 0) and K (comp 512, pad rows = bk), swizzled
  #pragma unroll
  for (int it = 0; it < 4; ++it) {
    int f  = it * 256 + tid;
    int r  = f >> 4;
    int c8 = f & 15;
    bool val; int tok = rowtok(r, val);
    int off = (r << 8) + (c8 << 4); off ^= (r & 7) << 4;
    bf16x8 q, k;
    if (val) {
      const unsigned short* base = qkvs + (size_t)tok * 1536 + h * 128 + c8 * 8;
      q = *(const bf16x8*)(base);
      k = *(const bf16x8*)(base + 512);
    } else {
      #pragma unroll
      for (int e = 0; e < 8; ++e) {
        q[e] = 0;
        k[e] = (short)f2b(bk[h * 128 + c8 * 8 + e]);
      }
    }
    *(bf16x8*)(qpb + off) = q;
    *(bf16x8*)(kbuf + off) = k;
  }
  // stage V transposed (comp 1024); pad rows from bv
  {
    int tok_r = tid & 63;
    int dg    = tid >> 6;
    bool val; int tok = rowtok(tok_r, val);
    bf16x8 vv[4];
    #pragma unroll
    for (int s4 = 0; s4 < 4; ++s4) {
      if (val) {
        vv[s4] = *(const bf16x8*)(qkvs + (size_t)tok * 1536 + 1024 + h * 128 + dg * 32 + s4 * 8);
      } else {
        #pragma unroll
        for (int e = 0; e < 8; ++e)
          vv[s4][e] = (short)f2b(bv[h * 128 + dg * 32 + s4 * 8 + e]);
      }
    }
    #pragma unroll
    for (int s4 = 0; s4 < 4; ++s4)
      #pragma unroll
      for (int e = 0; e < 8; ++e) {
        int d = dg * 32 + s4 * 8 + e;
        int off = (d << 7) + (tok_r << 1); off ^= (d & 7) << 4;
        *(unsigned short*)(vtb + off) = (unsigned short)vv[s4][e];
      }
  }
  __syncthreads();

  // QK^T from LDS (wave owns 16 q-rows)
  f32x4 sacc[4];
  #pragma unroll
  for (int nt = 0; nt < 4; ++nt) sacc[nt] = (f32x4){0.f, 0.f, 0.f, 0.f};
  #pragma unroll
  for (int kk = 0; kk < 128; kk += 32) {
    int ka = kk + kl;
    int qr = wvid * 16 + l15;
    int qo = (qr << 8) + (ka << 1); qo ^= (qr & 7) << 4;
    bf16x8 afr = *(const bf16x8*)(qpb + qo);
    #pragma unroll
    for (int nt = 0; nt < 4; ++nt) {
      int jr = nt * 16 + l15;
      int o2 = (jr << 8) + (ka << 1); o2 ^= (jr & 7) << 4;
      bf16x8 bfr = *(const bf16x8*)(kbuf + o2);
      sacc[nt] = __builtin_amdgcn_mfma_f32_16x16x32_bf16(afr, bfr, sacc[nt], 0, 0, 0);
    }
  }
  __syncthreads();   // all Q reads done before P overwrites qpb

  // softmax, P -> qpb (8KB region)
  #pragma unroll
  for (int rg = 0; rg < 4; ++rg) {
    float mx = -3.0e38f;
    #pragma unroll
    for (int nt = 0; nt < 4; ++nt) mx = fmaxf(mx, sacc[nt][rg]);
    #pragma unroll
    for (int dd = 1; dd < 16; dd <<= 1) mx = fmaxf(mx, __shfl_xor(mx, dd, 64));
    float s = 0.f, e[4];
    #pragma unroll
    for (int nt = 0; nt < 4; ++nt) { e[nt] = __expf((sacc[nt][rg] - mx) * SCALE); s += e[nt]; }
    #pragma unroll
    for (int dd = 1; dd < 16; dd <<= 1) s += __shfl_xor(s, dd, 64);
    float inv = 1.f / s;
    int row = wvid * 16 + rbase + rg;
    #pragma unroll
    for (int nt = 0; nt < 4; ++nt) {
      int col = nt * 16 + l15;
      int off = (row << 7) + (col << 1); off ^= (row & 7) << 4;
      *(unsigned short*)(qpb + off) = f2b(e[nt] * inv);
    }
  }
  __syncthreads();

  // PV
  f32x4 pacc[4][2];
  #pragma unroll
  for (int mt = 0; mt < 4; ++mt)
    #pragma unroll
    for (int nt = 0; nt < 2; ++nt) pacc[mt][nt] = (f32x4){0.f, 0.f, 0.f, 0.f};
  #pragma unroll
  for (int kk = 0; kk < 64; kk += 32) {
    int ka = kk + kl;
    bf16x8 afr[4];
    #pragma unroll
    for (int mt = 0; mt < 4; ++mt) {
      int row = mt * 16 + l15;
      int off = (row << 7) + (ka << 1); off ^= (row & 7) << 4;
      afr[mt] = *(const bf16x8*)(qpb + off);
    }
    bf16x8 bfr[2];
    #pragma unroll
    for (int nt = 0; nt < 2; ++nt) {
      int d = wvid * 32 + nt * 16 + l15;
      int off = (d << 7) + (ka << 1); off ^= (d & 7) << 4;
      bfr[nt] = *(const bf16x8*)(vtb + off);
    }
    #pragma unroll
    for (int mt = 0; mt < 4; ++mt)
      #pragma unroll
      for (int nt = 0; nt < 2; ++nt)
        pacc[mt][nt] = __builtin_amdgcn_mfma_f32_16x16x32_bf16(afr[mt], bfr[nt], pacc[mt][nt], 0, 0, 0);
  }
  // write attn over Q component (valid tokens only; disjoint (tok, head))
  #pragma unroll
  for (int mt = 0; mt < 4; ++mt)
    #pragma unroll
    for (int rg = 0; rg < 4; ++rg) {
      int r = mt * 16 + rbase + rg;
      bool val; int tok = rowtok(r, val);
      if (val) {
        unsigned short* po = qkvs + (size_t)tok * 1536 + h * 128;
        #pragma unroll
        for (int nt = 0; nt < 2; ++nt)
          po[wvid * 32 + nt * 16 + l15] = f2b(pacc[mt][nt][rg]);
      }
    }
}

// ===== K3: m97-style output proj: [103680x512(Q cols)] @ Wo^T + bo ==========
extern "C" __global__ __launch_bounds__(256, 4)
void proj_m97(const unsigned short* __restrict__ qkvs,   // attn in Q cols, stride 1536
              const unsigned short* __restrict__ wo,     // [512][512] bf16
              const float* __restrict__ bo,
              float* __restrict__ out)
{
  __shared__ char As[16384];
  __shared__ char Bs[16384];

  const int tid   = threadIdx.x;
  const int wvid  = tid >> 6;
  const int lane  = tid & 63;
  const int l15   = lane & 15;
  const int rbase = (lane >> 4) << 2;

  // 3240 = 8 * 405; tile-major within XCD chunk (4 col-blocks share A tile)
  const int i    = blockIdx.x;
  const int work = (i & 7) * 405 + (i >> 3);
  const int t0   = (work >> 2) * 128;
  const int j0   = (work & 3) * 128;

  const int lr = lane >> 3;
  const int lc = (lane & 7) ^ lr;
  const unsigned short* gA = qkvs + (size_t)(t0 + wvid * 32 + lr) * 1536 + lc * 8;
  const unsigned short* gB = wo + (size_t)(j0 + wvid * 32 + lr) * 512 + lc * 8;
  char* lA = As + wvid * 4096;
  char* lB = Bs + wvid * 4096;

  f32x4 acc[4][4];
  #pragma unroll
  for (int mt = 0; mt < 4; ++mt)
    #pragma unroll
    for (int nt = 0; nt < 4; ++nt) acc[mt][nt] = (f32x4){0.f, 0.f, 0.f, 0.f};

  const int wr = (wvid >> 1) * 64, wc = (wvid & 1) * 64;

  for (int kk = 0; kk < 512; kk += 64) {
    #pragma unroll
    for (int ii = 0; ii < 4; ++ii) {
      g2lds16(gA + (size_t)ii * 8 * 1536 + kk, lA + ii * 1024);
      g2lds16(gB + (size_t)ii * 8 * 512 + kk, lB + ii * 1024);
    }
    __syncthreads();
    #pragma unroll
    for (int ks = 0; ks < 2; ++ks) {
      const int lchunk = ks * 4 + (lane >> 4);
      bf16x8 afr[4], bfr[4];
      #pragma unroll
      for (int mt = 0; mt < 4; ++mt) {
        int row = wr + mt * 16 + l15;
        afr[mt] = *(const bf16x8*)(As + row * 128 + ((lchunk ^ (row & 7)) << 4));
      }
      #pragma unroll
      for (int nt = 0; nt < 4; ++nt) {
        int col = wc + nt * 16 + l15;
        bfr[nt] = *(const bf16x8*)(Bs + col * 128 + ((lchunk ^ (col & 7)) << 4));
      }
      #pragma unroll
      for (int mt = 0; mt < 4; ++mt)
        #pragma unroll
        for (int nt = 0; nt < 4; ++nt)
          acc[mt][nt] = __builtin_amdgcn_mfma_f32_16x16x32_bf16(afr[mt], bfr[nt], acc[mt][nt], 0, 0, 0);
    }
    __syncthreads();
  }

  #pragma unroll
  for (int nt = 0; nt < 4; ++nt) {
    int col = j0 + wc + nt * 16 + l15;
    float bi = bo[col];
    #pragma unroll
    for (int mt = 0; mt < 4; ++mt)
      #pragma unroll
      for (int rg = 0; rg < 4; ++rg) {
        int row = t0 + wr + mt * 16 + rbase + rg;
        out[(size_t)row * 512 + col] = acc[mt][nt][rg] + bi;
      }
  }
}

// ===== TIER 2 fallback: round-7 fused kernel + window-order proj ============
extern "C" __global__ __launch_bounds__(256, 1)
void qkv_attn(const float* __restrict__ x,
              const unsigned short* __restrict__ wbf,
              const float* __restrict__ bq, const float* __restrict__ bk,
              const float* __restrict__ bv,
              unsigned short* __restrict__ slab)
{
  __shared__ char smem[73728];
  char* qb = smem + 32768;
  char* kb = smem + 49152;
  char* pb = smem + 65536;

  const int tid   = threadIdx.x;
  const int wvid  = tid >> 6;
  const int lane  = tid & 63;
  const int l15   = lane & 15;
  const int kl    = (lane >> 4) << 3;
  const int rbase = (lane >> 4) << 2;

  const int blk = blockIdx.x;
  const int b   = blk / NWIN;
  const int w   = blk - b * NWIN;
  const int wy  = w / GWt, wx = w - wy * GWt;

  for (int it = 0; it < 32; ++it) {
    int f  = it * 256 + tid;
    int r  = f >> 7;
    int c4 = f & 127;
    int gy = wy * 8 + (r >> 3), gx = wx * 8 + (r & 7);
    float4 v = make_float4(0.f, 0.f, 0.f, 0.f);
    if (gy < Ht && gx < Wt)
      v = *(const float4*)(x + ((size_t)b * NTOK + gy * Wt + gx) * C + c4 * 4);
    u16x4 o;
    o[0] = f2b(v.x); o[1] = f2b(v.y); o[2] = f2b(v.z); o[3] = f2b(v.w);
    int lc  = c4 & 63;
    int off = (r << 9) + (lc << 3);
    off ^= (r & 7) << 4;
    off += (c4 >> 6) * 32768;
    *(u16x4*)(smem + off) = o;
  }
  __syncthreads();

  bf16x8 xr[4][8];
  #pragma unroll
  for (int mt = 0; mt < 4; ++mt) {
    int row = mt * 16 + l15;
    #pragma unroll
    for (int s = 0; s < 8; ++s) {
      int off = (row << 9) + ((s * 32 + kl) << 1);
      off ^= (row & 7) << 4;
      xr[mt][s] = *(const bf16x8*)(smem + 32768 + off);
    }
  }
  __syncthreads();

  auto gemm_r = [&](const unsigned short* wm, int h, f32x4 (&acc)[4][2]) {
    #pragma unroll
    for (int mt = 0; mt < 4; ++mt)
      #pragma unroll
      for (int nt = 0; nt < 2; ++nt) acc[mt][nt] = (f32x4){0.f, 0.f, 0.f, 0.f};
    #pragma unroll
    for (int s = 0; s < 16; ++s) {
      int ka = s * 32 + kl;
      bf16x8 afr[4];
      if (s < 8) {
        #pragma unroll
        for (int mt = 0; mt < 4; ++mt) {
          int row = mt * 16 + l15;
          int off = (row << 9) + (ka << 1);
          off ^= (row & 7) << 4;
          afr[mt] = *(const bf16x8*)(smem + off);
        }
      } else {
        #pragma unroll
        for (int mt = 0; mt < 4; ++mt) afr[mt] = xr[mt][s - 8];
      }
      bf16x8 bfr[2];
      #pragma unroll
      for (int nt = 0; nt < 2; ++nt) {
        int jg = h * 128 + wvid * 32 + nt * 16 + l15;
        bfr[nt] = *(const bf16x8*)(wm + (size_t)jg * 512 + ka);
      }
      #pragma unroll
      for (int mt = 0; mt < 4; ++mt)
        #pragma unroll
        for (int nt = 0; nt < 2; ++nt)
          acc[mt][nt] = __builtin_amdgcn_mfma_f32_16x16x32_bf16(afr[mt], bfr[nt], acc[mt][nt], 0, 0, 0);
    }
  };

  auto store_rm = [&](f32x4 (&acc)[4][2], char* base, const float* bias, int h) {
    #pragma unroll
    for (int nt = 0; nt < 2; ++nt) {
      int col = wvid * 32 + nt * 16 + l15;
      float bi = bias[h * 128 + col];
      #pragma unroll
      for (int mt = 0; mt < 4; ++mt)
        #pragma unroll
        for (int rg = 0; rg < 4; ++rg) {
          int row = mt * 16 + rbase + rg;
          int off = (row << 8) + (col << 1);
          off ^= (row & 7) << 4;
          *(unsigned short*)(base + off) = f2b(acc[mt][nt][rg] + bi);
        }
    }
  };

  unsigned short* sl = slab + (size_t)blk * 32768;

  for (int h = 0; h < 4; ++h) {
    {
      f32x4 acc[4][2];
      gemm_r(wbf + 0 * 262144, h, acc);
      store_rm(acc, qb, bq, h);
      gemm_r(wbf + 1 * 262144, h, acc);
      store_rm(acc, kb, bk, h);
    }
    __syncthreads();
    f32x4 vacc[4][2];
    {
      f32x4 sacc[4];
      #pragma unroll
      for (int nt = 0; nt < 4; ++nt) sacc[nt] = (f32x4){0.f, 0.f, 0.f, 0.f};
      #pragma unroll
      for (int kk = 0; kk < 128; kk += 32) {
        int ka = kk + kl;
        int row = wvid * 16 + l15;
        int off = (row << 8) + (ka << 1); off ^= (row & 7) << 4;
        bf16x8 afr = *(const bf16x8*)(qb + off);
        #pragma unroll
        for (int nt = 0; nt < 4; ++nt) {
          int jr = nt * 16 + l15;
          int o2 = (jr << 8) + (ka << 1); o2 ^= (jr & 7) << 4;
          bf16x8 bfr = *(const bf16x8*)(kb + o2);
          sacc[nt] = __builtin_amdgcn_mfma_f32_16x16x32_bf16(afr, bfr, sacc[nt], 0, 0, 0);
        }
      }
      #pragma unroll
      for (int rg = 0; rg < 4; ++rg) {
        float mx = -3.0e38f;
        #pragma unroll
        for (int nt = 0; nt < 4; ++nt) mx = fmaxf(mx, sacc[nt][rg]);
        #pragma unroll
        for (int dd = 1; dd < 16; dd <<= 1) mx = fmaxf(mx, __shfl_xor(mx, dd, 64));
        float s = 0.f, e[4];
        #pragma unroll
        for (int nt = 0; nt < 4; ++nt) { e[nt] = __expf((sacc[nt][rg] - mx) * SCALE); s += e[nt]; }
        #pragma unroll
        for (int dd = 1; dd < 16; dd <<= 1) s += __shfl_xor(s, dd, 64);
        float inv = 1.f / s;
        int row = wvid * 16 + rbase + rg;
        #pragma unroll
        for (int nt = 0; nt < 4; ++nt) {
          int col = nt * 16 + l15;
          int off = (row << 7) + (col << 1); off ^= (row & 7) << 4;
          *(unsigned short*)(pb + off) = f2b(e[nt] * inv);
        }
      }
      gemm_r(wbf + 2 * 262144, h, vacc);
    }
    __syncthreads();
    {
      #pragma unroll
      for (int nt = 0; nt < 2; ++nt) {
        int d = wvid * 32 + nt * 16 + l15;
        float bi = bv[h * 128 + d];
        #pragma unroll
        for (int mt = 0; mt < 4; ++mt) {
          int j0 = mt * 16 + rbase;
          u16x4 pk;
          #pragma unroll
          for (int rg = 0; rg < 4; ++rg) pk[rg] = f2b(vacc[mt][nt][rg] + bi);
          int off = (d << 7) + (j0 << 1); off ^= (d & 7) << 4;
          *(u16x4*)(kb + off) = pk;
        }
      }
    }
    __syncthreads();
    {
      f32x4 pacc[4][2];
      #pragma unroll
      for (int mt = 0; mt < 4; ++mt)
        #pragma unroll
        for (int nt = 0; nt < 2; ++nt) pacc[mt][nt] = (f32x4){0.f, 0.f, 0.f, 0.f};
      #pragma unroll
      for (int kk = 0; kk < 64; kk += 32) {
        int ka = kk + kl;
        bf16x8 afr[4];
        #pragma unroll
        for (int mt = 0; mt < 4; ++mt) {
          int row = mt * 16 + l15;
          int off = (row << 7) + (ka << 1); off ^= (row & 7) << 4;
          afr[mt] = *(const bf16x8*)(pb + off);
        }
        bf16x8 bfr[2];
        #pragma unroll
        for (int nt = 0; nt < 2; ++nt) {
          int d = wvid * 32 + nt * 16 + l15;
          int off = (d << 7) + (ka << 1); off ^= (d & 7) << 4;
          bfr[nt] = *(const bf16x8*)(kb + off);
        }
        #pragma unroll
        for (int mt = 0; mt < 4; ++mt)
          #pragma unroll
          for (int nt = 0; nt < 2; ++nt)
            pacc[mt][nt] = __builtin_amdgcn_mfma_f32_16x16x32_bf16(afr[mt], bfr[nt], pacc[mt][nt], 0, 0, 0);
      }
      #pragma unroll
      for (int nt = 0; nt < 2; ++nt) {
        int d = wvid * 32 + nt * 16 + l15;
        #pragma unroll
        for (int mt = 0; mt < 4; ++mt)
          #pragma unroll
          for (int rg = 0; rg < 4; ++rg) {
            int row = mt * 16 + rbase + rg;
            sl[row * 512 + h * 128 + d] = f2b(pacc[mt][nt][rg]);
          }
      }
    }
    __syncthreads();
  }
}

extern "C" __global__ __launch_bounds__(256, 2)
void proj_win(const unsigned short* __restrict__ slab,
              const unsigned short* __restrict__ wo,
              const float* __restrict__ bo,
              float* __restrict__ out)
{
  __shared__ char smem[65536];
  const int tid   = threadIdx.x;
  const int wvid  = tid >> 6;
  const int lane  = tid & 63;
  const int l15   = lane & 15;
  const int kl    = (lane >> 4) << 3;
  const int rbase = (lane >> 4) << 2;

  const int blk = blockIdx.x;
  const int b   = blk / NWIN;
  const int w   = blk - b * NWIN;
  const int wy  = w / GWt, wx = w - wy * GWt;

  const unsigned short* src = slab + (size_t)blk * 32768;
  for (int it = 0; it < 16; ++it) {
    int f  = it * 256 + tid;
    int r  = f >> 6;
    int c8 = f & 63;
    bf16x8 v = *(const bf16x8*)(src + r * 512 + c8 * 8);
    int off = (r << 10) + (c8 << 4);
    off ^= (r & 7) << 4;
    *(bf16x8*)(smem + off) = v;
  }
  __syncthreads();

  for (int half = 0; half < 2; ++half) {
    f32x4 acc[4][4];
    #pragma unroll
    for (int mt = 0; mt < 4; ++mt)
      #pragma unroll
      for (int nt = 0; nt < 4; ++nt) acc[mt][nt] = (f32x4){0.f, 0.f, 0.f, 0.f};
    #pragma unroll 2
    for (int kk = 0; kk < 512; kk += 32) {
      int ka = kk + kl;
      bf16x8 afr[4];
      #pragma unroll
      for (int mt = 0; mt < 4; ++mt) {
        int row = mt * 16 + l15;
        int off = (row << 10) + (ka << 1); off ^= (row & 7) << 4;
        afr[mt] = *(const bf16x8*)(smem + off);
      }
      bf16x8 bfr[4];
      #pragma unroll
      for (int nt = 0; nt < 4; ++nt) {
        int j = wvid * 128 + half * 64 + nt * 16 + l15;
        bfr[nt] = *(const bf16x8*)(wo + (size_t)j * 512 + ka);
      }
      #pragma unroll
      for (int mt = 0; mt < 4; ++mt)
        #pragma unroll
        for (int nt = 0; nt < 4; ++nt)
          acc[mt][nt] = __builtin_amdgcn_mfma_f32_16x16x32_bf16(afr[mt], bfr[nt], acc[mt][nt], 0, 0, 0);
    }
    #pragma unroll
    for (int mt = 0; mt < 4; ++mt)
      #pragma unroll
      for (int rg = 0; rg < 4; ++rg) {
        int r = mt * 16 + rbase + rg;
        int gy = wy * 8 + (r >> 3), gx = wx * 8 + (r & 7);
        if (gy < Ht && gx < Wt) {
          float* po = out + ((size_t)b * NTOK + gy * Wt + gx) * C;
          #pragma unroll
          for (int nt = 0; nt < 4; ++nt) {
            int j = wvid * 128 + half * 64 + nt * 16 + l15;
            po[j] = acc[mt][nt][rg] + bo[j];
          }
        }
      }
  }
}

extern "C" void kernel_launch(void* const* d_in, const int* in_sizes, int n_in,
                              void* d_out, int out_size, void* d_ws, size_t ws_size,
                              hipStream_t stream) {
  const float* x  = (const float*)d_in[0];
  const float* Wq = (const float*)d_in[2];
  const float* bq = (const float*)d_in[3];
  const float* Wk = (const float*)d_in[4];
  const float* bk = (const float*)d_in[5];
  const float* Wv = (const float*)d_in[6];
  const float* bv = (const float*)d_in[7];
  const float* Wo = (const float*)d_in[8];
  const float* bo = (const float*)d_in[9];
  unsigned short* wbf = (unsigned short*)d_ws;

  cvt_weights<<<1024, 256, 0, stream>>>(Wq, Wk, Wv, Wo, wbf);

  const size_t need_full = (WOFF + QKVE) * 2;     // ~321 MB
  const size_t need_r7   = (WOFF + SLABE) * 2;    // ~119 MB

  if (ws_size >= need_full) {
    unsigned short* qkvs = wbf + WOFF;
    qkv_f32<<<9720, 256, 0, stream>>>(x, wbf, bq, bk, bv, qkvs);
    attn_tok<<<dim3(NBLK, 4), 256, 0, stream>>>(qkvs, bk, bv);
    proj_m97<<<3240, 256, 0, stream>>>(qkvs, wbf + 3 * 262144, bo, (float*)d_out);
  } else if (ws_size >= need_r7) {
    unsigned short* slab = wbf + WOFF;
    qkv_attn<<<NBLK, 256, 0, stream>>>(x, wbf, bq, bk, bv, slab);
    proj_win<<<NBLK, 256, 0, stream>>>(slab, wbf + 3 * 262144, bo, (float*)d_out);
  }
}

// Round 16
// 499.753 us; speedup vs baseline: 1.2596x; 1.2596x over previous
//
#include <hip/hip_runtime.h>
#include <hip/hip_bf16.h>

using bf16x8 = __attribute__((ext_vector_type(8))) short;
using f32x4  = __attribute__((ext_vector_type(4))) float;
using u16x4  = __attribute__((ext_vector_type(4))) unsigned short;

constexpr int Ht = 60, Wt = 108, C = 512;
constexpr int GWt = 14, NWIN = 112, NTOK = Ht * Wt, BT = 16;
constexpr int NBLK = BT * NWIN;                    // 1792 windows
constexpr int MROWS = BT * NTOK;                   // 103680 = 810*128
constexpr float SCALE = 0.08838834764831845f;      // 1/sqrt(128)
constexpr size_t WOFF  = 4 * 262144;               // weights elems (bf16)
constexpr size_t QKVE  = (size_t)MROWS * 1536;     // fused slab elems
constexpr size_t SLABE = (size_t)NBLK * 64 * 512;  // tier-2 slab elems

typedef __attribute__((address_space(3))) void lds_void;
typedef const __attribute__((address_space(1))) void g_void;
__device__ __forceinline__ void g2lds16(const void* g, void* l) {
  __builtin_amdgcn_global_load_lds((g_void*)g, (lds_void*)l, 16, 0, 0);
}

__device__ __forceinline__ unsigned short f2b(float f) {   // f32 -> bf16 RNE
  union { float f; unsigned u; } v; v.f = f;
  unsigned r = v.u + 0x7fffu + ((v.u >> 16) & 1u);
  return (unsigned short)(r >> 16);
}
__device__ __forceinline__ bf16x8 cvt8(float4 a, float4 b) {
  union { bf16x8 v; __hip_bfloat162 h[4]; } u;
  u.h[0] = __float22bfloat162_rn(make_float2(a.x, a.y));
  u.h[1] = __float22bfloat162_rn(make_float2(a.z, a.w));
  u.h[2] = __float22bfloat162_rn(make_float2(b.x, b.y));
  u.h[3] = __float22bfloat162_rn(make_float2(b.z, b.w));
  return u.v;
}

__global__ void cvt_weights(const float* __restrict__ a, const float* __restrict__ b,
                            const float* __restrict__ c, const float* __restrict__ d,
                            unsigned short* __restrict__ dst) {
  int i = blockIdx.x * blockDim.x + threadIdx.x;
  int m  = i >> 16;
  int o4 = i & 65535;
  const float* src = (m == 0) ? a : (m == 1) ? b : (m == 2) ? c : d;
  float4 v = *(const float4*)(src + (size_t)o4 * 4);
  u16x4 o;
  o[0] = f2b(v.x); o[1] = f2b(v.y); o[2] = f2b(v.z); o[3] = f2b(v.w);
  *(u16x4*)(dst + (size_t)m * 262144 + (size_t)o4 * 4) = o;
}

// ===== K0: x f32 -> bf16 token-order (into d_out scratch) ===================
extern "C" __global__ void xcvt_tok(const float* __restrict__ x,
                                    unsigned short* __restrict__ xb) {
  size_t idx = ((size_t)blockIdx.x * 256 + threadIdx.x) * 8;
  float4 a = *(const float4*)(x + idx);
  float4 b = *(const float4*)(x + idx + 4);
  *(bf16x8*)(xb + idx) = cvt8(a, b);
}

// ===== K1: m97-style fused QKV GEMM: [103680x512] @ [1536x512]^T ============
extern "C" __global__ __launch_bounds__(256, 4)
void qkv_m97(const unsigned short* __restrict__ xb,   // [MROWS][512] bf16
             const unsigned short* __restrict__ wf,   // [1536][512] bf16 fused
             const float* __restrict__ bq, const float* __restrict__ bk,
             const float* __restrict__ bv,
             unsigned short* __restrict__ qkvs)       // [MROWS][1536] bf16
{
  __shared__ char As[16384];   // [128][64] bf16, phys chunk = logical ^ (row&7)
  __shared__ char Bs[16384];

  const int tid   = threadIdx.x;
  const int wvid  = tid >> 6;
  const int lane  = tid & 63;
  const int l15   = lane & 15;
  const int rbase = (lane >> 4) << 2;

  const int i    = blockIdx.x;
  const int work = (i & 7) * 1215 + (i >> 3);
  const int t0   = (work / 12) * 128;
  const int j0   = (work % 12) * 128;

  const int lr = lane >> 3;
  const int lc = (lane & 7) ^ lr;
  const unsigned short* gA = xb + (size_t)(t0 + wvid * 32 + lr) * 512 + lc * 8;
  const unsigned short* gB = wf + (size_t)(j0 + wvid * 32 + lr) * 512 + lc * 8;
  char* lA = As + wvid * 4096;
  char* lB = Bs + wvid * 4096;

  f32x4 acc[4][4];
  #pragma unroll
  for (int mt = 0; mt < 4; ++mt)
    #pragma unroll
    for (int nt = 0; nt < 4; ++nt) acc[mt][nt] = (f32x4){0.f, 0.f, 0.f, 0.f};

  const int wr = (wvid >> 1) * 64, wc = (wvid & 1) * 64;

  for (int kk = 0; kk < 512; kk += 64) {
    #pragma unroll
    for (int ii = 0; ii < 4; ++ii) {
      g2lds16(gA + (size_t)ii * 8 * 512 + kk, lA + ii * 1024);
      g2lds16(gB + (size_t)ii * 8 * 512 + kk, lB + ii * 1024);
    }
    __syncthreads();
    #pragma unroll
    for (int ks = 0; ks < 2; ++ks) {
      const int lchunk = ks * 4 + (lane >> 4);
      bf16x8 afr[4], bfr[4];
      #pragma unroll
      for (int mt = 0; mt < 4; ++mt) {
        int row = wr + mt * 16 + l15;
        afr[mt] = *(const bf16x8*)(As + row * 128 + ((lchunk ^ (row & 7)) << 4));
      }
      #pragma unroll
      for (int nt = 0; nt < 4; ++nt) {
        int col = wc + nt * 16 + l15;
        bfr[nt] = *(const bf16x8*)(Bs + col * 128 + ((lchunk ^ (col & 7)) << 4));
      }
      #pragma unroll
      for (int mt = 0; mt < 4; ++mt)
        #pragma unroll
        for (int nt = 0; nt < 4; ++nt)
          acc[mt][nt] = __builtin_amdgcn_mfma_f32_16x16x32_bf16(afr[mt], bfr[nt], acc[mt][nt], 0, 0, 0);
    }
    __syncthreads();
  }

  const int mloc = j0 >> 9;
  const float* bias = (mloc == 0) ? bq : (mloc == 1) ? bk : bv;
  const int jb = j0 & 511;
  #pragma unroll
  for (int nt = 0; nt < 4; ++nt) {
    int col = wc + nt * 16 + l15;
    float bi = bias[jb + col];
    #pragma unroll
    for (int mt = 0; mt < 4; ++mt)
      #pragma unroll
      for (int rg = 0; rg < 4; ++rg) {
        int row = t0 + wr + mt * 16 + rbase + rg;
        qkvs[(size_t)row * 1536 + j0 + col] = f2b(acc[mt][nt][rg] + bi);
      }
  }
}

// ===== K2: per-(window,head) attention. Q staged in LDS, buffer reused as P =
extern "C" __global__ __launch_bounds__(256, 3)
void attn_tok(unsigned short* __restrict__ qkvs,    // Q cols aliased as attn out
              const float* __restrict__ bk, const float* __restrict__ bv)
{
  __shared__ char kbuf[16384];
  __shared__ char vtb[16384];
  __shared__ char qpb[16384];          // Q [64][128] swz; reused as P [64][64]

  const int tid   = threadIdx.x;
  const int wvid  = tid >> 6;
  const int lane  = tid & 63;
  const int l15   = lane & 15;
  const int kl    = (lane >> 4) << 3;
  const int rbase = (lane >> 4) << 2;

  const int w   = blockIdx.x;
  const int h   = blockIdx.y;
  const int b   = w / NWIN;
  const int win = w - b * NWIN;
  const int wy  = win / GWt, wx = win - wy * GWt;
  const int bt0 = b * NTOK;

  auto rowtok = [&](int r, bool& val) {
    int gy = wy * 8 + (r >> 3), gx = wx * 8 + (r & 7);
    val = (gy < Ht) && (gx < Wt);
    return bt0 + gy * Wt + gx;
  };

  // stage Q (comp 0, pad rows = 0) and K (comp 512, pad rows = bk), swizzled
  #pragma unroll
  for (int it = 0; it < 4; ++it) {
    int f  = it * 256 + tid;
    int r  = f >> 4;
    int c8 = f & 15;
    bool val; int tok = rowtok(r, val);
    int off = (r << 8) + (c8 << 4); off ^= (r & 7) << 4;
    bf16x8 q, k;
    if (val) {
      const unsigned short* base = qkvs + (size_t)tok * 1536 + h * 128 + c8 * 8;
      q = *(const bf16x8*)(base);
      k = *(const bf16x8*)(base + 512);
    } else {
      #pragma unroll
      for (int e = 0; e < 8; ++e) {
        q[e] = 0;
        k[e] = (short)f2b(bk[h * 128 + c8 * 8 + e]);
      }
    }
    *(bf16x8*)(qpb + off) = q;
    *(bf16x8*)(kbuf + off) = k;
  }
  // stage V transposed (comp 1024); pad rows from bv
  {
    int tok_r = tid & 63;
    int dg    = tid >> 6;
    bool val; int tok = rowtok(tok_r, val);
    bf16x8 vv[4];
    #pragma unroll
    for (int s4 = 0; s4 < 4; ++s4) {
      if (val) {
        vv[s4] = *(const bf16x8*)(qkvs + (size_t)tok * 1536 + 1024 + h * 128 + dg * 32 + s4 * 8);
      } else {
        #pragma unroll
        for (int e = 0; e < 8; ++e)
          vv[s4][e] = (short)f2b(bv[h * 128 + dg * 32 + s4 * 8 + e]);
      }
    }
    #pragma unroll
    for (int s4 = 0; s4 < 4; ++s4)
      #pragma unroll
      for (int e = 0; e < 8; ++e) {
        int d = dg * 32 + s4 * 8 + e;
        int off = (d << 7) + (tok_r << 1); off ^= (d & 7) << 4;
        *(unsigned short*)(vtb + off) = (unsigned short)vv[s4][e];
      }
  }
  __syncthreads();

  // QK^T from LDS (wave owns 16 q-rows)
  f32x4 sacc[4];
  #pragma unroll
  for (int nt = 0; nt < 4; ++nt) sacc[nt] = (f32x4){0.f, 0.f, 0.f, 0.f};
  #pragma unroll
  for (int kk = 0; kk < 128; kk += 32) {
    int ka = kk + kl;
    int qr = wvid * 16 + l15;
    int qo = (qr << 8) + (ka << 1); qo ^= (qr & 7) << 4;
    bf16x8 afr = *(const bf16x8*)(qpb + qo);
    #pragma unroll
    for (int nt = 0; nt < 4; ++nt) {
      int jr = nt * 16 + l15;
      int o2 = (jr << 8) + (ka << 1); o2 ^= (jr & 7) << 4;
      bf16x8 bfr = *(const bf16x8*)(kbuf + o2);
      sacc[nt] = __builtin_amdgcn_mfma_f32_16x16x32_bf16(afr, bfr, sacc[nt], 0, 0, 0);
    }
  }
  __syncthreads();   // all Q reads done before P overwrites qpb

  // softmax, P -> qpb (8KB region)
  #pragma unroll
  for (int rg = 0; rg < 4; ++rg) {
    float mx = -3.0e38f;
    #pragma unroll
    for (int nt = 0; nt < 4; ++nt) mx = fmaxf(mx, sacc[nt][rg]);
    #pragma unroll
    for (int dd = 1; dd < 16; dd <<= 1) mx = fmaxf(mx, __shfl_xor(mx, dd, 64));
    float s = 0.f, e[4];
    #pragma unroll
    for (int nt = 0; nt < 4; ++nt) { e[nt] = __expf((sacc[nt][rg] - mx) * SCALE); s += e[nt]; }
    #pragma unroll
    for (int dd = 1; dd < 16; dd <<= 1) s += __shfl_xor(s, dd, 64);
    float inv = 1.f / s;
    int row = wvid * 16 + rbase + rg;
    #pragma unroll
    for (int nt = 0; nt < 4; ++nt) {
      int col = nt * 16 + l15;
      int off = (row << 7) + (col << 1); off ^= (row & 7) << 4;
      *(unsigned short*)(qpb + off) = f2b(e[nt] * inv);
    }
  }
  __syncthreads();

  // PV
  f32x4 pacc[4][2];
  #pragma unroll
  for (int mt = 0; mt < 4; ++mt)
    #pragma unroll
    for (int nt = 0; nt < 2; ++nt) pacc[mt][nt] = (f32x4){0.f, 0.f, 0.f, 0.f};
  #pragma unroll
  for (int kk = 0; kk < 64; kk += 32) {
    int ka = kk + kl;
    bf16x8 afr[4];
    #pragma unroll
    for (int mt = 0; mt < 4; ++mt) {
      int row = mt * 16 + l15;
      int off = (row << 7) + (ka << 1); off ^= (row & 7) << 4;
      afr[mt] = *(const bf16x8*)(qpb + off);
    }
    bf16x8 bfr[2];
    #pragma unroll
    for (int nt = 0; nt < 2; ++nt) {
      int d = wvid * 32 + nt * 16 + l15;
      int off = (d << 7) + (ka << 1); off ^= (d & 7) << 4;
      bfr[nt] = *(const bf16x8*)(vtb + off);
    }
    #pragma unroll
    for (int mt = 0; mt < 4; ++mt)
      #pragma unroll
      for (int nt = 0; nt < 2; ++nt)
        pacc[mt][nt] = __builtin_amdgcn_mfma_f32_16x16x32_bf16(afr[mt], bfr[nt], pacc[mt][nt], 0, 0, 0);
  }
  // write attn over Q component (valid tokens only; disjoint (tok, head))
  #pragma unroll
  for (int mt = 0; mt < 4; ++mt)
    #pragma unroll
    for (int rg = 0; rg < 4; ++rg) {
      int r = mt * 16 + rbase + rg;
      bool val; int tok = rowtok(r, val);
      if (val) {
        unsigned short* po = qkvs + (size_t)tok * 1536 + h * 128;
        #pragma unroll
        for (int nt = 0; nt < 2; ++nt)
          po[wvid * 32 + nt * 16 + l15] = f2b(pacc[mt][nt][rg]);
      }
    }
}

// ===== K3: m97-style output proj: [103680x512(Q cols)] @ Wo^T + bo ==========
extern "C" __global__ __launch_bounds__(256, 4)
void proj_m97(const unsigned short* __restrict__ qkvs,   // attn in Q cols, stride 1536
              const unsigned short* __restrict__ wo,     // [512][512] bf16
              const float* __restrict__ bo,
              float* __restrict__ out)
{
  __shared__ char As[16384];
  __shared__ char Bs[16384];

  const int tid   = threadIdx.x;
  const int wvid  = tid >> 6;
  const int lane  = tid & 63;
  const int l15   = lane & 15;
  const int rbase = (lane >> 4) << 2;

  // 3240 = 8 * 405; tile-major within XCD chunk (4 col-blocks share A tile)
  const int i    = blockIdx.x;
  const int work = (i & 7) * 405 + (i >> 3);
  const int t0   = (work >> 2) * 128;
  const int j0   = (work & 3) * 128;

  const int lr = lane >> 3;
  const int lc = (lane & 7) ^ lr;
  const unsigned short* gA = qkvs + (size_t)(t0 + wvid * 32 + lr) * 1536 + lc * 8;
  const unsigned short* gB = wo + (size_t)(j0 + wvid * 32 + lr) * 512 + lc * 8;
  char* lA = As + wvid * 4096;
  char* lB = Bs + wvid * 4096;

  f32x4 acc[4][4];
  #pragma unroll
  for (int mt = 0; mt < 4; ++mt)
    #pragma unroll
    for (int nt = 0; nt < 4; ++nt) acc[mt][nt] = (f32x4){0.f, 0.f, 0.f, 0.f};

  const int wr = (wvid >> 1) * 64, wc = (wvid & 1) * 64;

  for (int kk = 0; kk < 512; kk += 64) {
    #pragma unroll
    for (int ii = 0; ii < 4; ++ii) {
      g2lds16(gA + (size_t)ii * 8 * 1536 + kk, lA + ii * 1024);
      g2lds16(gB + (size_t)ii * 8 * 512 + kk, lB + ii * 1024);
    }
    __syncthreads();
    #pragma unroll
    for (int ks = 0; ks < 2; ++ks) {
      const int lchunk = ks * 4 + (lane >> 4);
      bf16x8 afr[4], bfr[4];
      #pragma unroll
      for (int mt = 0; mt < 4; ++mt) {
        int row = wr + mt * 16 + l15;
        afr[mt] = *(const bf16x8*)(As + row * 128 + ((lchunk ^ (row & 7)) << 4));
      }
      #pragma unroll
      for (int nt = 0; nt < 4; ++nt) {
        int col = wc + nt * 16 + l15;
        bfr[nt] = *(const bf16x8*)(Bs + col * 128 + ((lchunk ^ (col & 7)) << 4));
      }
      #pragma unroll
      for (int mt = 0; mt < 4; ++mt)
        #pragma unroll
        for (int nt = 0; nt < 4; ++nt)
          acc[mt][nt] = __builtin_amdgcn_mfma_f32_16x16x32_bf16(afr[mt], bfr[nt], acc[mt][nt], 0, 0, 0);
    }
    __syncthreads();
  }

  #pragma unroll
  for (int nt = 0; nt < 4; ++nt) {
    int col = j0 + wc + nt * 16 + l15;
    float bi = bo[col];
    #pragma unroll
    for (int mt = 0; mt < 4; ++mt)
      #pragma unroll
      for (int rg = 0; rg < 4; ++rg) {
        int row = t0 + wr + mt * 16 + rbase + rg;
        out[(size_t)row * 512 + col] = acc[mt][nt][rg] + bi;
      }
  }
}

// ===== TIER 2 fallback: round-7 fused kernel + window-order proj ============
extern "C" __global__ __launch_bounds__(256, 1)
void qkv_attn(const float* __restrict__ x,
              const unsigned short* __restrict__ wbf,
              const float* __restrict__ bq, const float* __restrict__ bk,
              const float* __restrict__ bv,
              unsigned short* __restrict__ slab)
{
  __shared__ char smem[73728];
  char* qb = smem + 32768;
  char* kb = smem + 49152;
  char* pb = smem + 65536;

  const int tid   = threadIdx.x;
  const int wvid  = tid >> 6;
  const int lane  = tid & 63;
  const int l15   = lane & 15;
  const int kl    = (lane >> 4) << 3;
  const int rbase = (lane >> 4) << 2;

  const int blk = blockIdx.x;
  const int b   = blk / NWIN;
  const int w   = blk - b * NWIN;
  const int wy  = w / GWt, wx = w - wy * GWt;

  for (int it = 0; it < 32; ++it) {
    int f  = it * 256 + tid;
    int r  = f >> 7;
    int c4 = f & 127;
    int gy = wy * 8 + (r >> 3), gx = wx * 8 + (r & 7);
    float4 v = make_float4(0.f, 0.f, 0.f, 0.f);
    if (gy < Ht && gx < Wt)
      v = *(const float4*)(x + ((size_t)b * NTOK + gy * Wt + gx) * C + c4 * 4);
    u16x4 o;
    o[0] = f2b(v.x); o[1] = f2b(v.y); o[2] = f2b(v.z); o[3] = f2b(v.w);
    int lc  = c4 & 63;
    int off = (r << 9) + (lc << 3);
    off ^= (r & 7) << 4;
    off += (c4 >> 6) * 32768;
    *(u16x4*)(smem + off) = o;
  }
  __syncthreads();

  bf16x8 xr[4][8];
  #pragma unroll
  for (int mt = 0; mt < 4; ++mt) {
    int row = mt * 16 + l15;
    #pragma unroll
    for (int s = 0; s < 8; ++s) {
      int off = (row << 9) + ((s * 32 + kl) << 1);
      off ^= (row & 7) << 4;
      xr[mt][s] = *(const bf16x8*)(smem + 32768 + off);
    }
  }
  __syncthreads();

  auto gemm_r = [&](const unsigned short* wm, int h, f32x4 (&acc)[4][2]) {
    #pragma unroll
    for (int mt = 0; mt < 4; ++mt)
      #pragma unroll
      for (int nt = 0; nt < 2; ++nt) acc[mt][nt] = (f32x4){0.f, 0.f, 0.f, 0.f};
    #pragma unroll
    for (int s = 0; s < 16; ++s) {
      int ka = s * 32 + kl;
      bf16x8 afr[4];
      if (s < 8) {
        #pragma unroll
        for (int mt = 0; mt < 4; ++mt) {
          int row = mt * 16 + l15;
          int off = (row << 9) + (ka << 1);
          off ^= (row & 7) << 4;
          afr[mt] = *(const bf16x8*)(smem + off);
        }
      } else {
        #pragma unroll
        for (int mt = 0; mt < 4; ++mt) afr[mt] = xr[mt][s - 8];
      }
      bf16x8 bfr[2];
      #pragma unroll
      for (int nt = 0; nt < 2; ++nt) {
        int jg = h * 128 + wvid * 32 + nt * 16 + l15;
        bfr[nt] = *(const bf16x8*)(wm + (size_t)jg * 512 + ka);
      }
      #pragma unroll
      for (int mt = 0; mt < 4; ++mt)
        #pragma unroll
        for (int nt = 0; nt < 2; ++nt)
          acc[mt][nt] = __builtin_amdgcn_mfma_f32_16x16x32_bf16(afr[mt], bfr[nt], acc[mt][nt], 0, 0, 0);
    }
  };

  auto store_rm = [&](f32x4 (&acc)[4][2], char* base, const float* bias, int h) {
    #pragma unroll
    for (int nt = 0; nt < 2; ++nt) {
      int col = wvid * 32 + nt * 16 + l15;
      float bi = bias[h * 128 + col];
      #pragma unroll
      for (int mt = 0; mt < 4; ++mt)
        #pragma unroll
        for (int rg = 0; rg < 4; ++rg) {
          int row = mt * 16 + rbase + rg;
          int off = (row << 8) + (col << 1);
          off ^= (row & 7) << 4;
          *(unsigned short*)(base + off) = f2b(acc[mt][nt][rg] + bi);
        }
    }
  };

  unsigned short* sl = slab + (size_t)blk * 32768;

  for (int h = 0; h < 4; ++h) {
    {
      f32x4 acc[4][2];
      gemm_r(wbf + 0 * 262144, h, acc);
      store_rm(acc, qb, bq, h);
      gemm_r(wbf + 1 * 262144, h, acc);
      store_rm(acc, kb, bk, h);
    }
    __syncthreads();
    f32x4 vacc[4][2];
    {
      f32x4 sacc[4];
      #pragma unroll
      for (int nt = 0; nt < 4; ++nt) sacc[nt] = (f32x4){0.f, 0.f, 0.f, 0.f};
      #pragma unroll
      for (int kk = 0; kk < 128; kk += 32) {
        int ka = kk + kl;
        int row = wvid * 16 + l15;
        int off = (row << 8) + (ka << 1); off ^= (row & 7) << 4;
        bf16x8 afr = *(const bf16x8*)(qb + off);
        #pragma unroll
        for (int nt = 0; nt < 4; ++nt) {
          int jr = nt * 16 + l15;
          int o2 = (jr << 8) + (ka << 1); o2 ^= (jr & 7) << 4;
          bf16x8 bfr = *(const bf16x8*)(kb + o2);
          sacc[nt] = __builtin_amdgcn_mfma_f32_16x16x32_bf16(afr, bfr, sacc[nt], 0, 0, 0);
        }
      }
      #pragma unroll
      for (int rg = 0; rg < 4; ++rg) {
        float mx = -3.0e38f;
        #pragma unroll
        for (int nt = 0; nt < 4; ++nt) mx = fmaxf(mx, sacc[nt][rg]);
        #pragma unroll
        for (int dd = 1; dd < 16; dd <<= 1) mx = fmaxf(mx, __shfl_xor(mx, dd, 64));
        float s = 0.f, e[4];
        #pragma unroll
        for (int nt = 0; nt < 4; ++nt) { e[nt] = __expf((sacc[nt][rg] - mx) * SCALE); s += e[nt]; }
        #pragma unroll
        for (int dd = 1; dd < 16; dd <<= 1) s += __shfl_xor(s, dd, 64);
        float inv = 1.f / s;
        int row = wvid * 16 + rbase + rg;
        #pragma unroll
        for (int nt = 0; nt < 4; ++nt) {
          int col = nt * 16 + l15;
          int off = (row << 7) + (col << 1); off ^= (row & 7) << 4;
          *(unsigned short*)(pb + off) = f2b(e[nt] * inv);
        }
      }
      gemm_r(wbf + 2 * 262144, h, vacc);
    }
    __syncthreads();
    {
      #pragma unroll
      for (int nt = 0; nt < 2; ++nt) {
        int d = wvid * 32 + nt * 16 + l15;
        float bi = bv[h * 128 + d];
        #pragma unroll
        for (int mt = 0; mt < 4; ++mt) {
          int j0 = mt * 16 + rbase;
          u16x4 pk;
          #pragma unroll
          for (int rg = 0; rg < 4; ++rg) pk[rg] = f2b(vacc[mt][nt][rg] + bi);
          int off = (d << 7) + (j0 << 1); off ^= (d & 7) << 4;
          *(u16x4*)(kb + off) = pk;
        }
      }
    }
    __syncthreads();
    {
      f32x4 pacc[4][2];
      #pragma unroll
      for (int mt = 0; mt < 4; ++mt)
        #pragma unroll
        for (int nt = 0; nt < 2; ++nt) pacc[mt][nt] = (f32x4){0.f, 0.f, 0.f, 0.f};
      #pragma unroll
      for (int kk = 0; kk < 64; kk += 32) {
        int ka = kk + kl;
        bf16x8 afr[4];
        #pragma unroll
        for (int mt = 0; mt < 4; ++mt) {
          int row = mt * 16 + l15;
          int off = (row << 7) + (ka << 1); off ^= (row & 7) << 4;
          afr[mt] = *(const bf16x8*)(pb + off);
        }
        bf16x8 bfr[2];
        #pragma unroll
        for (int nt = 0; nt < 2; ++nt) {
          int d = wvid * 32 + nt * 16 + l15;
          int off = (d << 7) + (ka << 1); off ^= (d & 7) << 4;
          bfr[nt] = *(const bf16x8*)(kb + off);
        }
        #pragma unroll
        for (int mt = 0; mt < 4; ++mt)
          #pragma unroll
          for (int nt = 0; nt < 2; ++nt)
            pacc[mt][nt] = __builtin_amdgcn_mfma_f32_16x16x32_bf16(afr[mt], bfr[nt], pacc[mt][nt], 0, 0, 0);
      }
      #pragma unroll
      for (int nt = 0; nt < 2; ++nt) {
        int d = wvid * 32 + nt * 16 + l15;
        #pragma unroll
        for (int mt = 0; mt < 4; ++mt)
          #pragma unroll
          for (int rg = 0; rg < 4; ++rg) {
            int row = mt * 16 + rbase + rg;
            sl[row * 512 + h * 128 + d] = f2b(pacc[mt][nt][rg]);
          }
      }
    }
    __syncthreads();
  }
}

extern "C" __global__ __launch_bounds__(256, 2)
void proj_win(const unsigned short* __restrict__ slab,
              const unsigned short* __restrict__ wo,
              const float* __restrict__ bo,
              float* __restrict__ out)
{
  __shared__ char smem[65536];
  const int tid   = threadIdx.x;
  const int wvid  = tid >> 6;
  const int lane  = tid & 63;
  const int l15   = lane & 15;
  const int kl    = (lane >> 4) << 3;
  const int rbase = (lane >> 4) << 2;

  const int blk = blockIdx.x;
  const int b   = blk / NWIN;
  const int w   = blk - b * NWIN;
  const int wy  = w / GWt, wx = w - wy * GWt;

  const unsigned short* src = slab + (size_t)blk * 32768;
  for (int it = 0; it < 16; ++it) {
    int f  = it * 256 + tid;
    int r  = f >> 6;
    int c8 = f & 63;
    bf16x8 v = *(const bf16x8*)(src + r * 512 + c8 * 8);
    int off = (r << 10) + (c8 << 4);
    off ^= (r & 7) << 4;
    *(bf16x8*)(smem + off) = v;
  }
  __syncthreads();

  for (int half = 0; half < 2; ++half) {
    f32x4 acc[4][4];
    #pragma unroll
    for (int mt = 0; mt < 4; ++mt)
      #pragma unroll
      for (int nt = 0; nt < 4; ++nt) acc[mt][nt] = (f32x4){0.f, 0.f, 0.f, 0.f};
    #pragma unroll 2
    for (int kk = 0; kk < 512; kk += 32) {
      int ka = kk + kl;
      bf16x8 afr[4];
      #pragma unroll
      for (int mt = 0; mt < 4; ++mt) {
        int row = mt * 16 + l15;
        int off = (row << 10) + (ka << 1); off ^= (row & 7) << 4;
        afr[mt] = *(const bf16x8*)(smem + off);
      }
      bf16x8 bfr[4];
      #pragma unroll
      for (int nt = 0; nt < 4; ++nt) {
        int j = wvid * 128 + half * 64 + nt * 16 + l15;
        bfr[nt] = *(const bf16x8*)(wo + (size_t)j * 512 + ka);
      }
      #pragma unroll
      for (int mt = 0; mt < 4; ++mt)
        #pragma unroll
        for (int nt = 0; nt < 4; ++nt)
          acc[mt][nt] = __builtin_amdgcn_mfma_f32_16x16x32_bf16(afr[mt], bfr[nt], acc[mt][nt], 0, 0, 0);
    }
    #pragma unroll
    for (int mt = 0; mt < 4; ++mt)
      #pragma unroll
      for (int rg = 0; rg < 4; ++rg) {
        int r = mt * 16 + rbase + rg;
        int gy = wy * 8 + (r >> 3), gx = wx * 8 + (r & 7);
        if (gy < Ht && gx < Wt) {
          float* po = out + ((size_t)b * NTOK + gy * Wt + gx) * C;
          #pragma unroll
          for (int nt = 0; nt < 4; ++nt) {
            int j = wvid * 128 + half * 64 + nt * 16 + l15;
            po[j] = acc[mt][nt][rg] + bo[j];
          }
        }
      }
  }
}

extern "C" void kernel_launch(void* const* d_in, const int* in_sizes, int n_in,
                              void* d_out, int out_size, void* d_ws, size_t ws_size,
                              hipStream_t stream) {
  const float* x  = (const float*)d_in[0];
  const float* Wq = (const float*)d_in[2];
  const float* bq = (const float*)d_in[3];
  const float* Wk = (const float*)d_in[4];
  const float* bk = (const float*)d_in[5];
  const float* Wv = (const float*)d_in[6];
  const float* bv = (const float*)d_in[7];
  const float* Wo = (const float*)d_in[8];
  const float* bo = (const float*)d_in[9];
  unsigned short* wbf = (unsigned short*)d_ws;

  cvt_weights<<<1024, 256, 0, stream>>>(Wq, Wk, Wv, Wo, wbf);

  const size_t need_full = (WOFF + QKVE) * 2;     // ~321 MB
  const size_t need_r7   = (WOFF + SLABE) * 2;    // ~119 MB

  if (ws_size >= need_full) {
    unsigned short* qkvs = wbf + WOFF;
    unsigned short* xb   = (unsigned short*)d_out;   // d_out as bf16-x scratch
    xcvt_tok<<<MROWS * 512 / 2048, 256, 0, stream>>>(x, xb);
    qkv_m97<<<9720, 256, 0, stream>>>(xb, wbf, bq, bk, bv, qkvs);
    attn_tok<<<dim3(NBLK, 4), 256, 0, stream>>>(qkvs, bk, bv);
    proj_m97<<<3240, 256, 0, stream>>>(qkvs, wbf + 3 * 262144, bo, (float*)d_out);
  } else if (ws_size >= need_r7) {
    unsigned short* slab = wbf + WOFF;
    qkv_attn<<<NBLK, 256, 0, stream>>>(x, wbf, bq, bk, bv, slab);
    proj_win<<<NBLK, 256, 0, stream>>>(slab, wbf + 3 * 262144, bo, (float*)d_out);
  }
}

// Round 17
// 495.121 us; speedup vs baseline: 1.2714x; 1.0094x over previous
//
#include <hip/hip_runtime.h>
#include <hip/hip_bf16.h>

using bf16x8 = __attribute__((ext_vector_type(8))) short;
using f32x4  = __attribute__((ext_vector_type(4))) float;
using u16x4  = __attribute__((ext_vector_type(4))) unsigned short;

constexpr int Ht = 60, Wt = 108, C = 512;
constexpr int GWt = 14, NWIN = 112, NTOK = Ht * Wt, BT = 16;
constexpr int NBLK = BT * NWIN;                    // 1792 windows
constexpr int MROWS = BT * NTOK;                   // 103680 = 810*128
constexpr float SCALE = 0.08838834764831845f;      // 1/sqrt(128)
constexpr size_t WOFF  = 4 * 262144;               // weights elems (bf16)
constexpr size_t QKVE  = (size_t)MROWS * 1536;     // fused slab elems
constexpr size_t SLABE = (size_t)NBLK * 64 * 512;  // tier-2 slab elems
constexpr int WBLK = 1024;                         // prep: weight blocks
constexpr int XBLK = MROWS * 512 / 2048;           // prep: x blocks (25920)

typedef __attribute__((address_space(3))) void lds_void;
typedef const __attribute__((address_space(1))) void g_void;
__device__ __forceinline__ void g2lds16(const void* g, void* l) {
  __builtin_amdgcn_global_load_lds((g_void*)g, (lds_void*)l, 16, 0, 0);
}

__device__ __forceinline__ unsigned short f2b(float f) {   // f32 -> bf16 RNE
  union { float f; unsigned u; } v; v.f = f;
  unsigned r = v.u + 0x7fffu + ((v.u >> 16) & 1u);
  return (unsigned short)(r >> 16);
}
__device__ __forceinline__ bf16x8 cvt8(float4 a, float4 b) {
  union { bf16x8 v; __hip_bfloat162 h[4]; } u;
  u.h[0] = __float22bfloat162_rn(make_float2(a.x, a.y));
  u.h[1] = __float22bfloat162_rn(make_float2(a.z, a.w));
  u.h[2] = __float22bfloat162_rn(make_float2(b.x, b.y));
  u.h[3] = __float22bfloat162_rn(make_float2(b.z, b.w));
  return u.v;
}

// ===== K0: fused prep — weights f32->bf16 (4x512x512) AND x f32->bf16 =======
extern "C" __global__ void prep(const float* __restrict__ x,
                                const float* __restrict__ Wq,
                                const float* __restrict__ Wk,
                                const float* __restrict__ Wv,
                                const float* __restrict__ Wo,
                                unsigned short* __restrict__ wdst,
                                unsigned short* __restrict__ xb) {
  int bid = blockIdx.x;
  if (bid < WBLK) {
    int i  = bid * 256 + threadIdx.x;          // 262144 threads, 4 f32 each
    int m  = i >> 16;
    int o4 = i & 65535;
    const float* src = (m == 0) ? Wq : (m == 1) ? Wk : (m == 2) ? Wv : Wo;
    float4 v = *(const float4*)(src + (size_t)o4 * 4);
    u16x4 o;
    o[0] = f2b(v.x); o[1] = f2b(v.y); o[2] = f2b(v.z); o[3] = f2b(v.w);
    *(u16x4*)(wdst + (size_t)m * 262144 + (size_t)o4 * 4) = o;
  } else {
    size_t idx = ((size_t)(bid - WBLK) * 256 + threadIdx.x) * 8;
    float4 a = *(const float4*)(x + idx);
    float4 b = *(const float4*)(x + idx + 4);
    *(bf16x8*)(xb + idx) = cvt8(a, b);
  }
}

// tier-2 still needs standalone weight conversion
__global__ void cvt_weights(const float* __restrict__ a, const float* __restrict__ b,
                            const float* __restrict__ c, const float* __restrict__ d,
                            unsigned short* __restrict__ dst) {
  int i = blockIdx.x * blockDim.x + threadIdx.x;
  int m  = i >> 16;
  int o4 = i & 65535;
  const float* src = (m == 0) ? a : (m == 1) ? b : (m == 2) ? c : d;
  float4 v = *(const float4*)(src + (size_t)o4 * 4);
  u16x4 o;
  o[0] = f2b(v.x); o[1] = f2b(v.y); o[2] = f2b(v.z); o[3] = f2b(v.w);
  *(u16x4*)(dst + (size_t)m * 262144 + (size_t)o4 * 4) = o;
}

// ===== K1: m97-style fused QKV GEMM: [103680x512] @ [1536x512]^T ============
extern "C" __global__ __launch_bounds__(256, 4)
void qkv_m97(const unsigned short* __restrict__ xb,   // [MROWS][512] bf16
             const unsigned short* __restrict__ wf,   // [1536][512] bf16 fused
             const float* __restrict__ bq, const float* __restrict__ bk,
             const float* __restrict__ bv,
             unsigned short* __restrict__ qkvs)       // [MROWS][1536] bf16
{
  __shared__ char As[16384];   // [128][64] bf16, phys chunk = logical ^ (row&7)
  __shared__ char Bs[16384];

  const int tid   = threadIdx.x;
  const int wvid  = tid >> 6;
  const int lane  = tid & 63;
  const int l15   = lane & 15;
  const int rbase = (lane >> 4) << 2;

  const int i    = blockIdx.x;
  const int work = (i & 7) * 1215 + (i >> 3);
  const int t0   = (work / 12) * 128;
  const int j0   = (work % 12) * 128;

  const int lr = lane >> 3;
  const int lc = (lane & 7) ^ lr;
  const unsigned short* gA = xb + (size_t)(t0 + wvid * 32 + lr) * 512 + lc * 8;
  const unsigned short* gB = wf + (size_t)(j0 + wvid * 32 + lr) * 512 + lc * 8;
  char* lA = As + wvid * 4096;
  char* lB = Bs + wvid * 4096;

  f32x4 acc[4][4];
  #pragma unroll
  for (int mt = 0; mt < 4; ++mt)
    #pragma unroll
    for (int nt = 0; nt < 4; ++nt) acc[mt][nt] = (f32x4){0.f, 0.f, 0.f, 0.f};

  const int wr = (wvid >> 1) * 64, wc = (wvid & 1) * 64;

  for (int kk = 0; kk < 512; kk += 64) {
    #pragma unroll
    for (int ii = 0; ii < 4; ++ii) {
      g2lds16(gA + (size_t)ii * 8 * 512 + kk, lA + ii * 1024);
      g2lds16(gB + (size_t)ii * 8 * 512 + kk, lB + ii * 1024);
    }
    __syncthreads();
    #pragma unroll
    for (int ks = 0; ks < 2; ++ks) {
      const int lchunk = ks * 4 + (lane >> 4);
      bf16x8 afr[4], bfr[4];
      #pragma unroll
      for (int mt = 0; mt < 4; ++mt) {
        int row = wr + mt * 16 + l15;
        afr[mt] = *(const bf16x8*)(As + row * 128 + ((lchunk ^ (row & 7)) << 4));
      }
      #pragma unroll
      for (int nt = 0; nt < 4; ++nt) {
        int col = wc + nt * 16 + l15;
        bfr[nt] = *(const bf16x8*)(Bs + col * 128 + ((lchunk ^ (col & 7)) << 4));
      }
      #pragma unroll
      for (int mt = 0; mt < 4; ++mt)
        #pragma unroll
        for (int nt = 0; nt < 4; ++nt)
          acc[mt][nt] = __builtin_amdgcn_mfma_f32_16x16x32_bf16(afr[mt], bfr[nt], acc[mt][nt], 0, 0, 0);
    }
    __syncthreads();
  }

  const int mloc = j0 >> 9;
  const float* bias = (mloc == 0) ? bq : (mloc == 1) ? bk : bv;
  const int jb = j0 & 511;
  #pragma unroll
  for (int nt = 0; nt < 4; ++nt) {
    int col = wc + nt * 16 + l15;
    float bi = bias[jb + col];
    #pragma unroll
    for (int mt = 0; mt < 4; ++mt)
      #pragma unroll
      for (int rg = 0; rg < 4; ++rg) {
        int row = t0 + wr + mt * 16 + rbase + rg;
        qkvs[(size_t)row * 1536 + j0 + col] = f2b(acc[mt][nt][rg] + bi);
      }
  }
}

// ===== K2: per-(window,head) attention. Q staged in LDS, buffer reused as P =
extern "C" __global__ __launch_bounds__(256, 3)
void attn_tok(unsigned short* __restrict__ qkvs,    // Q cols aliased as attn out
              const float* __restrict__ bk, const float* __restrict__ bv)
{
  __shared__ char kbuf[16384];
  __shared__ char vtb[16384];
  __shared__ char qpb[16384];          // Q [64][128] swz; reused as P [64][64]

  const int tid   = threadIdx.x;
  const int wvid  = tid >> 6;
  const int lane  = tid & 63;
  const int l15   = lane & 15;
  const int kl    = (lane >> 4) << 3;
  const int rbase = (lane >> 4) << 2;

  const int w   = blockIdx.x;
  const int h   = blockIdx.y;
  const int b   = w / NWIN;
  const int win = w - b * NWIN;
  const int wy  = win / GWt, wx = win - wy * GWt;
  const int bt0 = b * NTOK;

  auto rowtok = [&](int r, bool& val) {
    int gy = wy * 8 + (r >> 3), gx = wx * 8 + (r & 7);
    val = (gy < Ht) && (gx < Wt);
    return bt0 + gy * Wt + gx;
  };

  // stage Q (comp 0, pad rows = 0) and K (comp 512, pad rows = bk), swizzled
  #pragma unroll
  for (int it = 0; it < 4; ++it) {
    int f  = it * 256 + tid;
    int r  = f >> 4;
    int c8 = f & 15;
    bool val; int tok = rowtok(r, val);
    int off = (r << 8) + (c8 << 4); off ^= (r & 7) << 4;
    bf16x8 q, k;
    if (val) {
      const unsigned short* base = qkvs + (size_t)tok * 1536 + h * 128 + c8 * 8;
      q = *(const bf16x8*)(base);
      k = *(const bf16x8*)(base + 512);
    } else {
      #pragma unroll
      for (int e = 0; e < 8; ++e) {
        q[e] = 0;
        k[e] = (short)f2b(bk[h * 128 + c8 * 8 + e]);
      }
    }
    *(bf16x8*)(qpb + off) = q;
    *(bf16x8*)(kbuf + off) = k;
  }
  // stage V transposed (comp 1024); pad rows from bv
  {
    int tok_r = tid & 63;
    int dg    = tid >> 6;
    bool val; int tok = rowtok(tok_r, val);
    bf16x8 vv[4];
    #pragma unroll
    for (int s4 = 0; s4 < 4; ++s4) {
      if (val) {
        vv[s4] = *(const bf16x8*)(qkvs + (size_t)tok * 1536 + 1024 + h * 128 + dg * 32 + s4 * 8);
      } else {
        #pragma unroll
        for (int e = 0; e < 8; ++e)
          vv[s4][e] = (short)f2b(bv[h * 128 + dg * 32 + s4 * 8 + e]);
      }
    }
    #pragma unroll
    for (int s4 = 0; s4 < 4; ++s4)
      #pragma unroll
      for (int e = 0; e < 8; ++e) {
        int d = dg * 32 + s4 * 8 + e;
        int off = (d << 7) + (tok_r << 1); off ^= (d & 7) << 4;
        *(unsigned short*)(vtb + off) = (unsigned short)vv[s4][e];
      }
  }
  __syncthreads();

  // QK^T from LDS (wave owns 16 q-rows)
  f32x4 sacc[4];
  #pragma unroll
  for (int nt = 0; nt < 4; ++nt) sacc[nt] = (f32x4){0.f, 0.f, 0.f, 0.f};
  #pragma unroll
  for (int kk = 0; kk < 128; kk += 32) {
    int ka = kk + kl;
    int qr = wvid * 16 + l15;
    int qo = (qr << 8) + (ka << 1); qo ^= (qr & 7) << 4;
    bf16x8 afr = *(const bf16x8*)(qpb + qo);
    #pragma unroll
    for (int nt = 0; nt < 4; ++nt) {
      int jr = nt * 16 + l15;
      int o2 = (jr << 8) + (ka << 1); o2 ^= (jr & 7) << 4;
      bf16x8 bfr = *(const bf16x8*)(kbuf + o2);
      sacc[nt] = __builtin_amdgcn_mfma_f32_16x16x32_bf16(afr, bfr, sacc[nt], 0, 0, 0);
    }
  }
  __syncthreads();   // all Q reads done before P overwrites qpb

  // softmax, P -> qpb (8KB region)
  #pragma unroll
  for (int rg = 0; rg < 4; ++rg) {
    float mx = -3.0e38f;
    #pragma unroll
    for (int nt = 0; nt < 4; ++nt) mx = fmaxf(mx, sacc[nt][rg]);
    #pragma unroll
    for (int dd = 1; dd < 16; dd <<= 1) mx = fmaxf(mx, __shfl_xor(mx, dd, 64));
    float s = 0.f, e[4];
    #pragma unroll
    for (int nt = 0; nt < 4; ++nt) { e[nt] = __expf((sacc[nt][rg] - mx) * SCALE); s += e[nt]; }
    #pragma unroll
    for (int dd = 1; dd < 16; dd <<= 1) s += __shfl_xor(s, dd, 64);
    float inv = 1.f / s;
    int row = wvid * 16 + rbase + rg;
    #pragma unroll
    for (int nt = 0; nt < 4; ++nt) {
      int col = nt * 16 + l15;
      int off = (row << 7) + (col << 1); off ^= (row & 7) << 4;
      *(unsigned short*)(qpb + off) = f2b(e[nt] * inv);
    }
  }
  __syncthreads();

  // PV
  f32x4 pacc[4][2];
  #pragma unroll
  for (int mt = 0; mt < 4; ++mt)
    #pragma unroll
    for (int nt = 0; nt < 2; ++nt) pacc[mt][nt] = (f32x4){0.f, 0.f, 0.f, 0.f};
  #pragma unroll
  for (int kk = 0; kk < 64; kk += 32) {
    int ka = kk + kl;
    bf16x8 afr[4];
    #pragma unroll
    for (int mt = 0; mt < 4; ++mt) {
      int row = mt * 16 + l15;
      int off = (row << 7) + (ka << 1); off ^= (row & 7) << 4;
      afr[mt] = *(const bf16x8*)(qpb + off);
    }
    bf16x8 bfr[2];
    #pragma unroll
    for (int nt = 0; nt < 2; ++nt) {
      int d = wvid * 32 + nt * 16 + l15;
      int off = (d << 7) + (ka << 1); off ^= (d & 7) << 4;
      bfr[nt] = *(const bf16x8*)(vtb + off);
    }
    #pragma unroll
    for (int mt = 0; mt < 4; ++mt)
      #pragma unroll
      for (int nt = 0; nt < 2; ++nt)
        pacc[mt][nt] = __builtin_amdgcn_mfma_f32_16x16x32_bf16(afr[mt], bfr[nt], pacc[mt][nt], 0, 0, 0);
  }
  // write attn over Q component (valid tokens only; disjoint (tok, head))
  #pragma unroll
  for (int mt = 0; mt < 4; ++mt)
    #pragma unroll
    for (int rg = 0; rg < 4; ++rg) {
      int r = mt * 16 + rbase + rg;
      bool val; int tok = rowtok(r, val);
      if (val) {
        unsigned short* po = qkvs + (size_t)tok * 1536 + h * 128;
        #pragma unroll
        for (int nt = 0; nt < 2; ++nt)
          po[wvid * 32 + nt * 16 + l15] = f2b(pacc[mt][nt][rg]);
      }
    }
}

// ===== K3: m97-style output proj: [103680x512(Q cols)] @ Wo^T + bo ==========
extern "C" __global__ __launch_bounds__(256, 4)
void proj_m97(const unsigned short* __restrict__ qkvs,   // attn in Q cols, stride 1536
              const unsigned short* __restrict__ wo,     // [512][512] bf16
              const float* __restrict__ bo,
              float* __restrict__ out)
{
  __shared__ char As[16384];
  __shared__ char Bs[16384];

  const int tid   = threadIdx.x;
  const int wvid  = tid >> 6;
  const int lane  = tid & 63;
  const int l15   = lane & 15;
  const int rbase = (lane >> 4) << 2;

  // 3240 = 8 * 405; tile-major within XCD chunk (4 col-blocks share A tile)
  const int i    = blockIdx.x;
  const int work = (i & 7) * 405 + (i >> 3);
  const int t0   = (work >> 2) * 128;
  const int j0   = (work & 3) * 128;

  const int lr = lane >> 3;
  const int lc = (lane & 7) ^ lr;
  const unsigned short* gA = qkvs + (size_t)(t0 + wvid * 32 + lr) * 1536 + lc * 8;
  const unsigned short* gB = wo + (size_t)(j0 + wvid * 32 + lr) * 512 + lc * 8;
  char* lA = As + wvid * 4096;
  char* lB = Bs + wvid * 4096;

  f32x4 acc[4][4];
  #pragma unroll
  for (int mt = 0; mt < 4; ++mt)
    #pragma unroll
    for (int nt = 0; nt < 4; ++nt) acc[mt][nt] = (f32x4){0.f, 0.f, 0.f, 0.f};

  const int wr = (wvid >> 1) * 64, wc = (wvid & 1) * 64;

  for (int kk = 0; kk < 512; kk += 64) {
    #pragma unroll
    for (int ii = 0; ii < 4; ++ii) {
      g2lds16(gA + (size_t)ii * 8 * 1536 + kk, lA + ii * 1024);
      g2lds16(gB + (size_t)ii * 8 * 512 + kk, lB + ii * 1024);
    }
    __syncthreads();
    #pragma unroll
    for (int ks = 0; ks < 2; ++ks) {
      const int lchunk = ks * 4 + (lane >> 4);
      bf16x8 afr[4], bfr[4];
      #pragma unroll
      for (int mt = 0; mt < 4; ++mt) {
        int row = wr + mt * 16 + l15;
        afr[mt] = *(const bf16x8*)(As + row * 128 + ((lchunk ^ (row & 7)) << 4));
      }
      #pragma unroll
      for (int nt = 0; nt < 4; ++nt) {
        int col = wc + nt * 16 + l15;
        bfr[nt] = *(const bf16x8*)(Bs + col * 128 + ((lchunk ^ (col & 7)) << 4));
      }
      #pragma unroll
      for (int mt = 0; mt < 4; ++mt)
        #pragma unroll
        for (int nt = 0; nt < 4; ++nt)
          acc[mt][nt] = __builtin_amdgcn_mfma_f32_16x16x32_bf16(afr[mt], bfr[nt], acc[mt][nt], 0, 0, 0);
    }
    __syncthreads();
  }

  #pragma unroll
  for (int nt = 0; nt < 4; ++nt) {
    int col = j0 + wc + nt * 16 + l15;
    float bi = bo[col];
    #pragma unroll
    for (int mt = 0; mt < 4; ++mt)
      #pragma unroll
      for (int rg = 0; rg < 4; ++rg) {
        int row = t0 + wr + mt * 16 + rbase + rg;
        out[(size_t)row * 512 + col] = acc[mt][nt][rg] + bi;
      }
  }
}

// ===== TIER 2 fallback: round-7 fused kernel + window-order proj ============
extern "C" __global__ __launch_bounds__(256, 1)
void qkv_attn(const float* __restrict__ x,
              const unsigned short* __restrict__ wbf,
              const float* __restrict__ bq, const float* __restrict__ bk,
              const float* __restrict__ bv,
              unsigned short* __restrict__ slab)
{
  __shared__ char smem[73728];
  char* qb = smem + 32768;
  char* kb = smem + 49152;
  char* pb = smem + 65536;

  const int tid   = threadIdx.x;
  const int wvid  = tid >> 6;
  const int lane  = tid & 63;
  const int l15   = lane & 15;
  const int kl    = (lane >> 4) << 3;
  const int rbase = (lane >> 4) << 2;

  const int blk = blockIdx.x;
  const int b   = blk / NWIN;
  const int w   = blk - b * NWIN;
  const int wy  = w / GWt, wx = w - wy * GWt;

  for (int it = 0; it < 32; ++it) {
    int f  = it * 256 + tid;
    int r  = f >> 7;
    int c4 = f & 127;
    int gy = wy * 8 + (r >> 3), gx = wx * 8 + (r & 7);
    float4 v = make_float4(0.f, 0.f, 0.f, 0.f);
    if (gy < Ht && gx < Wt)
      v = *(const float4*)(x + ((size_t)b * NTOK + gy * Wt + gx) * C + c4 * 4);
    u16x4 o;
    o[0] = f2b(v.x); o[1] = f2b(v.y); o[2] = f2b(v.z); o[3] = f2b(v.w);
    int lc  = c4 & 63;
    int off = (r << 9) + (lc << 3);
    off ^= (r & 7) << 4;
    off += (c4 >> 6) * 32768;
    *(u16x4*)(smem + off) = o;
  }
  __syncthreads();

  bf16x8 xr[4][8];
  #pragma unroll
  for (int mt = 0; mt < 4; ++mt) {
    int row = mt * 16 + l15;
    #pragma unroll
    for (int s = 0; s < 8; ++s) {
      int off = (row << 9) + ((s * 32 + kl) << 1);
      off ^= (row & 7) << 4;
      xr[mt][s] = *(const bf16x8*)(smem + 32768 + off);
    }
  }
  __syncthreads();

  auto gemm_r = [&](const unsigned short* wm, int h, f32x4 (&acc)[4][2]) {
    #pragma unroll
    for (int mt = 0; mt < 4; ++mt)
      #pragma unroll
      for (int nt = 0; nt < 2; ++nt) acc[mt][nt] = (f32x4){0.f, 0.f, 0.f, 0.f};
    #pragma unroll
    for (int s = 0; s < 16; ++s) {
      int ka = s * 32 + kl;
      bf16x8 afr[4];
      if (s < 8) {
        #pragma unroll
        for (int mt = 0; mt < 4; ++mt) {
          int row = mt * 16 + l15;
          int off = (row << 9) + (ka << 1);
          off ^= (row & 7) << 4;
          afr[mt] = *(const bf16x8*)(smem + off);
        }
      } else {
        #pragma unroll
        for (int mt = 0; mt < 4; ++mt) afr[mt] = xr[mt][s - 8];
      }
      bf16x8 bfr[2];
      #pragma unroll
      for (int nt = 0; nt < 2; ++nt) {
        int jg = h * 128 + wvid * 32 + nt * 16 + l15;
        bfr[nt] = *(const bf16x8*)(wm + (size_t)jg * 512 + ka);
      }
      #pragma unroll
      for (int mt = 0; mt < 4; ++mt)
        #pragma unroll
        for (int nt = 0; nt < 2; ++nt)
          acc[mt][nt] = __builtin_amdgcn_mfma_f32_16x16x32_bf16(afr[mt], bfr[nt], acc[mt][nt], 0, 0, 0);
    }
  };

  auto store_rm = [&](f32x4 (&acc)[4][2], char* base, const float* bias, int h) {
    #pragma unroll
    for (int nt = 0; nt < 2; ++nt) {
      int col = wvid * 32 + nt * 16 + l15;
      float bi = bias[h * 128 + col];
      #pragma unroll
      for (int mt = 0; mt < 4; ++mt)
        #pragma unroll
        for (int rg = 0; rg < 4; ++rg) {
          int row = mt * 16 + rbase + rg;
          int off = (row << 8) + (col << 1);
          off ^= (row & 7) << 4;
          *(unsigned short*)(base + off) = f2b(acc[mt][nt][rg] + bi);
        }
    }
  };

  unsigned short* sl = slab + (size_t)blk * 32768;

  for (int h = 0; h < 4; ++h) {
    {
      f32x4 acc[4][2];
      gemm_r(wbf + 0 * 262144, h, acc);
      store_rm(acc, qb, bq, h);
      gemm_r(wbf + 1 * 262144, h, acc);
      store_rm(acc, kb, bk, h);
    }
    __syncthreads();
    f32x4 vacc[4][2];
    {
      f32x4 sacc[4];
      #pragma unroll
      for (int nt = 0; nt < 4; ++nt) sacc[nt] = (f32x4){0.f, 0.f, 0.f, 0.f};
      #pragma unroll
      for (int kk = 0; kk < 128; kk += 32) {
        int ka = kk + kl;
        int row = wvid * 16 + l15;
        int off = (row << 8) + (ka << 1); off ^= (row & 7) << 4;
        bf16x8 afr = *(const bf16x8*)(qb + off);
        #pragma unroll
        for (int nt = 0; nt < 4; ++nt) {
          int jr = nt * 16 + l15;
          int o2 = (jr << 8) + (ka << 1); o2 ^= (jr & 7) << 4;
          bf16x8 bfr = *(const bf16x8*)(kb + o2);
          sacc[nt] = __builtin_amdgcn_mfma_f32_16x16x32_bf16(afr, bfr, sacc[nt], 0, 0, 0);
        }
      }
      #pragma unroll
      for (int rg = 0; rg < 4; ++rg) {
        float mx = -3.0e38f;
        #pragma unroll
        for (int nt = 0; nt < 4; ++nt) mx = fmaxf(mx, sacc[nt][rg]);
        #pragma unroll
        for (int dd = 1; dd < 16; dd <<= 1) mx = fmaxf(mx, __shfl_xor(mx, dd, 64));
        float s = 0.f, e[4];
        #pragma unroll
        for (int nt = 0; nt < 4; ++nt) { e[nt] = __expf((sacc[nt][rg] - mx) * SCALE); s += e[nt]; }
        #pragma unroll
        for (int dd = 1; dd < 16; dd <<= 1) s += __shfl_xor(s, dd, 64);
        float inv = 1.f / s;
        int row = wvid * 16 + rbase + rg;
        #pragma unroll
        for (int nt = 0; nt < 4; ++nt) {
          int col = nt * 16 + l15;
          int off = (row << 7) + (col << 1); off ^= (row & 7) << 4;
          *(unsigned short*)(pb + off) = f2b(e[nt] * inv);
        }
      }
      gemm_r(wbf + 2 * 262144, h, vacc);
    }
    __syncthreads();
    {
      #pragma unroll
      for (int nt = 0; nt < 2; ++nt) {
        int d = wvid * 32 + nt * 16 + l15;
        float bi = bv[h * 128 + d];
        #pragma unroll
        for (int mt = 0; mt < 4; ++mt) {
          int j0 = mt * 16 + rbase;
          u16x4 pk;
          #pragma unroll
          for (int rg = 0; rg < 4; ++rg) pk[rg] = f2b(vacc[mt][nt][rg] + bi);
          int off = (d << 7) + (j0 << 1); off ^= (d & 7) << 4;
          *(u16x4*)(kb + off) = pk;
        }
      }
    }
    __syncthreads();
    {
      f32x4 pacc[4][2];
      #pragma unroll
      for (int mt = 0; mt < 4; ++mt)
        #pragma unroll
        for (int nt = 0; nt < 2; ++nt) pacc[mt][nt] = (f32x4){0.f, 0.f, 0.f, 0.f};
      #pragma unroll
      for (int kk = 0; kk < 64; kk += 32) {
        int ka = kk + kl;
        bf16x8 afr[4];
        #pragma unroll
        for (int mt = 0; mt < 4; ++mt) {
          int row = mt * 16 + l15;
          int off = (row << 7) + (ka << 1); off ^= (row & 7) << 4;
          afr[mt] = *(const bf16x8*)(pb + off);
        }
        bf16x8 bfr[2];
        #pragma unroll
        for (int nt = 0; nt < 2; ++nt) {
          int d = wvid * 32 + nt * 16 + l15;
          int off = (d << 7) + (ka << 1); off ^= (d & 7) << 4;
          bfr[nt] = *(const bf16x8*)(kb + off);
        }
        #pragma unroll
        for (int mt = 0; mt < 4; ++mt)
          #pragma unroll
          for (int nt = 0; nt < 2; ++nt)
            pacc[mt][nt] = __builtin_amdgcn_mfma_f32_16x16x32_bf16(afr[mt], bfr[nt], pacc[mt][nt], 0, 0, 0);
      }
      #pragma unroll
      for (int nt = 0; nt < 2; ++nt) {
        int d = wvid * 32 + nt * 16 + l15;
        #pragma unroll
        for (int mt = 0; mt < 4; ++mt)
          #pragma unroll
          for (int rg = 0; rg < 4; ++rg) {
            int row = mt * 16 + rbase + rg;
            sl[row * 512 + h * 128 + d] = f2b(pacc[mt][nt][rg]);
          }
      }
    }
    __syncthreads();
  }
}

extern "C" __global__ __launch_bounds__(256, 2)
void proj_win(const unsigned short* __restrict__ slab,
              const unsigned short* __restrict__ wo,
              const float* __restrict__ bo,
              float* __restrict__ out)
{
  __shared__ char smem[65536];
  const int tid   = threadIdx.x;
  const int wvid  = tid >> 6;
  const int lane  = tid & 63;
  const int l15   = lane & 15;
  const int kl    = (lane >> 4) << 3;
  const int rbase = (lane >> 4) << 2;

  const int blk = blockIdx.x;
  const int b   = blk / NWIN;
  const int w   = blk - b * NWIN;
  const int wy  = w / GWt, wx = w - wy * GWt;

  const unsigned short* src = slab + (size_t)blk * 32768;
  for (int it = 0; it < 16; ++it) {
    int f  = it * 256 + tid;
    int r  = f >> 6;
    int c8 = f & 63;
    bf16x8 v = *(const bf16x8*)(src + r * 512 + c8 * 8);
    int off = (r << 10) + (c8 << 4);
    off ^= (r & 7) << 4;
    *(bf16x8*)(smem + off) = v;
  }
  __syncthreads();

  for (int half = 0; half < 2; ++half) {
    f32x4 acc[4][4];
    #pragma unroll
    for (int mt = 0; mt < 4; ++mt)
      #pragma unroll
      for (int nt = 0; nt < 4; ++nt) acc[mt][nt] = (f32x4){0.f, 0.f, 0.f, 0.f};
    #pragma unroll 2
    for (int kk = 0; kk < 512; kk += 32) {
      int ka = kk + kl;
      bf16x8 afr[4];
      #pragma unroll
      for (int mt = 0; mt < 4; ++mt) {
        int row = mt * 16 + l15;
        int off = (row << 10) + (ka << 1); off ^= (row & 7) << 4;
        afr[mt] = *(const bf16x8*)(smem + off);
      }
      bf16x8 bfr[4];
      #pragma unroll
      for (int nt = 0; nt < 4; ++nt) {
        int j = wvid * 128 + half * 64 + nt * 16 + l15;
        bfr[nt] = *(const bf16x8*)(wo + (size_t)j * 512 + ka);
      }
      #pragma unroll
      for (int mt = 0; mt < 4; ++mt)
        #pragma unroll
        for (int nt = 0; nt < 4; ++nt)
          acc[mt][nt] = __builtin_amdgcn_mfma_f32_16x16x32_bf16(afr[mt], bfr[nt], acc[mt][nt], 0, 0, 0);
    }
    #pragma unroll
    for (int mt = 0; mt < 4; ++mt)
      #pragma unroll
      for (int rg = 0; rg < 4; ++rg) {
        int r = mt * 16 + rbase + rg;
        int gy = wy * 8 + (r >> 3), gx = wx * 8 + (r & 7);
        if (gy < Ht && gx < Wt) {
          float* po = out + ((size_t)b * NTOK + gy * Wt + gx) * C;
          #pragma unroll
          for (int nt = 0; nt < 4; ++nt) {
            int j = wvid * 128 + half * 64 + nt * 16 + l15;
            po[j] = acc[mt][nt][rg] + bo[j];
          }
        }
      }
  }
}

extern "C" void kernel_launch(void* const* d_in, const int* in_sizes, int n_in,
                              void* d_out, int out_size, void* d_ws, size_t ws_size,
                              hipStream_t stream) {
  const float* x  = (const float*)d_in[0];
  const float* Wq = (const float*)d_in[2];
  const float* bq = (const float*)d_in[3];
  const float* Wk = (const float*)d_in[4];
  const float* bk = (const float*)d_in[5];
  const float* Wv = (const float*)d_in[6];
  const float* bv = (const float*)d_in[7];
  const float* Wo = (const float*)d_in[8];
  const float* bo = (const float*)d_in[9];
  unsigned short* wbf = (unsigned short*)d_ws;

  const size_t need_full = (WOFF + QKVE) * 2;     // ~321 MB
  const size_t need_r7   = (WOFF + SLABE) * 2;    // ~119 MB

  if (ws_size >= need_full) {
    unsigned short* qkvs = wbf + WOFF;
    unsigned short* xb   = (unsigned short*)d_out;   // d_out as bf16-x scratch
    prep<<<WBLK + XBLK, 256, 0, stream>>>(x, Wq, Wk, Wv, Wo, wbf, xb);
    qkv_m97<<<9720, 256, 0, stream>>>(xb, wbf, bq, bk, bv, qkvs);
    attn_tok<<<dim3(NBLK, 4), 256, 0, stream>>>(qkvs, bk, bv);
    proj_m97<<<3240, 256, 0, stream>>>(qkvs, wbf + 3 * 262144, bo, (float*)d_out);
  } else if (ws_size >= need_r7) {
    unsigned short* slab = wbf + WOFF;
    cvt_weights<<<1024, 256, 0, stream>>>(Wq, Wk, Wv, Wo, wbf);
    qkv_attn<<<NBLK, 256, 0, stream>>>(x, wbf, bq, bk, bv, slab);
    proj_win<<<NBLK, 256, 0, stream>>>(slab, wbf + 3 * 262144, bo, (float*)d_out);
  }
}